// Round 1
// 774.403 us; speedup vs baseline: 1.0256x; 1.0256x over previous
//
#include <hip/hip_runtime.h>
#include <stdint.h>
#include <stddef.h>

typedef __bf16 bf16x8 __attribute__((ext_vector_type(8)));
typedef short short8 __attribute__((ext_vector_type(8)));
typedef float floatx4 __attribute__((ext_vector_type(4)));
typedef unsigned short ushort4v __attribute__((ext_vector_type(4)));

__device__ __forceinline__ unsigned short f2bf(float f){
  unsigned int u = __float_as_uint(f);
  u += 0x7fffu + ((u >> 16) & 1u);
  return (unsigned short)(u >> 16);
}
__device__ __forceinline__ float bf2f(unsigned short s){
  return __uint_as_float(((unsigned int)s) << 16);
}
__device__ __forceinline__ void gl2lds16(const void* g, void* l){
  __builtin_amdgcn_global_load_lds((const __attribute__((address_space(1))) void*)g,
                                   (__attribute__((address_space(3))) void*)l, 16, 0, 0);
}

// ---------------- fp32 -> bf16 flat convert (n multiple of 1024) ----------------
__global__ __launch_bounds__(256) void conv_f32_bf16(const float* __restrict__ in,
                                                     unsigned short* __restrict__ out){
  int t = blockIdx.x * 256 + threadIdx.x;
  floatx4 v = *(const floatx4*)(in + (size_t)t * 4);
  ushort4v o;
#pragma unroll
  for (int j = 0; j < 4; ++j) o[j] = f2bf(v[j]);
  *(ushort4v*)(out + (size_t)t * 4) = o;
}

// ---------------- transpose+convert: fp32 [Kd,Nd] -> bf16 [Nd,Kd] ----------------
__global__ __launch_bounds__(256) void transpose_cvt(const float* __restrict__ in,
                                                     unsigned short* __restrict__ out,
                                                     int Kd, int Nd){
  __shared__ __align__(16) unsigned short tile[64 * 80];
  int n0 = blockIdx.x * 64, k0 = blockIdx.y * 64;
  int t = threadIdx.x;
#pragma unroll
  for (int it = 0; it < 2; ++it){
    int rr = (t >> 3) + it * 32;
    int cc = t & 7;
    const float* src = in + (size_t)(k0 + rr) * Nd + n0 + cc * 8;
    floatx4 a = *(const floatx4*)src;
    floatx4 b = *(const floatx4*)(src + 4);
    short8 s;
#pragma unroll
    for (int j = 0; j < 4; ++j){ s[j] = (short)f2bf(a[j]); s[j + 4] = (short)f2bf(b[j]); }
    *(short8*)&tile[rr * 80 + cc * 8] = s;
  }
  __syncthreads();
#pragma unroll
  for (int it = 0; it < 2; ++it){
    int nr = (t >> 3) + it * 32;
    int kc = t & 7;
    short8 v;
#pragma unroll
    for (int j = 0; j < 8; ++j) v[j] = (short)tile[(kc * 8 + j) * 80 + nr];
    *(short8*)(out + (size_t)(n0 + nr) * Kd + k0 + kc * 8) = v;
  }
}

// ---------------- GEMM: C[M,n] = A[M,4096] * Wt^T, Wt given as [N,4096] bf16 ----------------
// Region by n0: [0,4096) -> oQ bf16 (ld 4096) or oF fp32 if f32out; [4096,5120) -> oK; [5120,6144) -> oVt transposed.
__global__ __launch_bounds__(256, 2) void gemm_bt(
    const unsigned short* __restrict__ A,
    const unsigned short* __restrict__ Wq,
    const unsigned short* __restrict__ Wk,
    const unsigned short* __restrict__ Wv,
    unsigned short* __restrict__ oQ,
    unsigned short* __restrict__ oK,
    unsigned short* __restrict__ oVt,
    float* __restrict__ oF, int f32out)
{
  __shared__ __align__(16) unsigned short As[128 * 64];
  __shared__ __align__(16) unsigned short Bs[128 * 64];
  const int tid = threadIdx.x;
  const int w = tid >> 6, lane = tid & 63, quad = lane >> 4, l15 = lane & 15;
  const int wm64 = (w >> 1) * 64, wn64 = (w & 1) * 64;
  const int m0 = blockIdx.y * 128;
  const int n0 = blockIdx.x * 128;

  const unsigned short* Wsrc;
  int nb, region;
  if (n0 < 4096)      { Wsrc = Wq; nb = n0;        region = 0; }
  else if (n0 < 5120) { Wsrc = Wk; nb = n0 - 4096; region = 1; }
  else                { Wsrc = Wv; nb = n0 - 5120; region = 2; }

  floatx4 acc[4][4];
#pragma unroll
  for (int i = 0; i < 4; ++i)
#pragma unroll
    for (int j = 0; j < 4; ++j) acc[i][j] = (floatx4){0.f, 0.f, 0.f, 0.f};

  const int rsub = lane >> 3, csub = lane & 7;

  for (int k0 = 0; k0 < 4096; k0 += 64){
#pragma unroll
    for (int i = 0; i < 4; ++i){
      int u = i * 4 + w;
      int r = u * 8 + rsub;
      gl2lds16(A    + ((size_t)(m0 + r) << 12) + k0 + ((csub ^ (r & 7)) << 3), (char*)As + u * 1024);
      gl2lds16(Wsrc + ((size_t)(nb + r) << 12) + k0 + ((csub ^ (r & 7)) << 3), (char*)Bs + u * 1024);
    }
    __syncthreads();
#pragma unroll
    for (int ks = 0; ks < 2; ++ks){
      bf16x8 af[4], bfr[4];
#pragma unroll
      for (int mt = 0; mt < 4; ++mt){
        int r = wm64 + mt * 16 + l15;
        int kc = ks * 4 + quad;
        af[mt] = *(const bf16x8*)&As[r * 64 + ((kc ^ (r & 7)) << 3)];
      }
#pragma unroll
      for (int nt = 0; nt < 4; ++nt){
        int r = wn64 + nt * 16 + l15;
        int kc = ks * 4 + quad;
        bfr[nt] = *(const bf16x8*)&Bs[r * 64 + ((kc ^ (r & 7)) << 3)];
      }
#pragma unroll
      for (int mt = 0; mt < 4; ++mt)
#pragma unroll
        for (int nt = 0; nt < 4; ++nt)
          acc[mt][nt] = __builtin_amdgcn_mfma_f32_16x16x32_bf16(af[mt], bfr[nt], acc[mt][nt], 0, 0, 0);
    }
    __syncthreads();
  }

  if (region == 0){
    if (f32out){
#pragma unroll
      for (int mt = 0; mt < 4; ++mt)
#pragma unroll
        for (int nt = 0; nt < 4; ++nt){
          int gn = n0 + wn64 + nt * 16 + l15;
#pragma unroll
          for (int rr = 0; rr < 4; ++rr){
            int gm = m0 + wm64 + mt * 16 + quad * 4 + rr;
            oF[((size_t)gm << 12) + gn] = acc[mt][nt][rr];
          }
        }
    } else {
#pragma unroll
      for (int mt = 0; mt < 4; ++mt)
#pragma unroll
        for (int nt = 0; nt < 4; ++nt){
          int gn = n0 + wn64 + nt * 16 + l15;
#pragma unroll
          for (int rr = 0; rr < 4; ++rr){
            int gm = m0 + wm64 + mt * 16 + quad * 4 + rr;
            oQ[((size_t)gm << 12) + gn] = f2bf(acc[mt][nt][rr]);
          }
        }
    }
  } else if (region == 1){
#pragma unroll
    for (int mt = 0; mt < 4; ++mt)
#pragma unroll
      for (int nt = 0; nt < 4; ++nt){
        int gn = n0 - 4096 + wn64 + nt * 16 + l15;
#pragma unroll
        for (int rr = 0; rr < 4; ++rr){
          int gm = m0 + wm64 + mt * 16 + quad * 4 + rr;
          oK[((size_t)gm << 10) + gn] = f2bf(acc[mt][nt][rr]);
        }
      }
  } else {
#pragma unroll
    for (int mt = 0; mt < 4; ++mt){
      int gm0 = m0 + wm64 + mt * 16 + quad * 4;
      int b = gm0 >> 11, s0 = gm0 & 2047;
#pragma unroll
      for (int nt = 0; nt < 4; ++nt){
        int dg = n0 - 5120 + wn64 + nt * 16 + l15;
        int kvh = dg >> 7, d = dg & 127;
        ushort4v pk;
#pragma unroll
        for (int rr = 0; rr < 4; ++rr) pk[rr] = f2bf(acc[mt][nt][rr]);
        *(ushort4v*)(oVt + (((size_t)(b * 8 + kvh) * 128 + d) * 2048 + s0)) = pk;
      }
    }
  }
}

// ---------------- RoPE apply (in-place on Q and K), sin/cos inline ----------------
// Q additionally folded with SM_SCALE*log2(e) so attention scores land in exp2 domain.
__global__ void rope_apply_k(unsigned short* __restrict__ Qb, unsigned short* __restrict__ Kb,
                             const int* __restrict__ pos){
  int t = blockIdx.x * 256 + threadIdx.x;  // 1,310,720 total
  unsigned short* base;
  int row, ch;
  bool isq = (t < 1048576);
  if (isq){ row = t >> 8; int c = t & 255; base = Qb + ((size_t)row << 12) + (c >> 3) * 128; ch = c & 7; }
  else { int t2 = t - 1048576; row = t2 >> 6; int c = t2 & 63; base = Kb + ((size_t)row << 10) + (c >> 3) * 128; ch = c & 7; }
  float p = (float)pos[row];
  const float qs = 0.08838834764831845f * 1.44269504088896340736f; // (1/sqrt(128))*log2(e)
  float sc_out = isq ? qs : 1.0f;
  int d0 = ch * 8;
  short8 x0 = *(short8*)(base + d0);
  short8 x1 = *(short8*)(base + d0 + 64);
  short8 y0, y1;
#pragma unroll
  for (int j = 0; j < 8; ++j){
    float ang = p * exp2f(-(float)(d0 + j) * 0.20762050593045952f); // log2(1e4)/64
    float sn = sinf(ang), cs = cosf(ang);
    float a  = bf2f((unsigned short)x0[j]);
    float bb = bf2f((unsigned short)x1[j]);
    y0[j] = (short)f2bf((a * cs - bb * sn) * sc_out);
    y1[j] = (short)f2bf((bb * cs + a * sn) * sc_out);
  }
  *(short8*)(base + d0)      = y0;
  *(short8*)(base + d0 + 64) = y1;
}

// ---------------- flash attention, sliding window 1024 ----------------
// grid (32 qtiles, 32 heads, 2 batch); block 256 = 4 waves; 16 q rows/wave.
// Scores arrive pre-scaled to exp2 domain (SM_SCALE*log2e folded into Q).
// Masking only on the diagonal tile (jt==qt), the window-edge tile (qt-jt==16),
// or when attention_mask has zeros in the tile (wave-ballot check).
__global__ __launch_bounds__(256, 4) void flash_swa(
    const unsigned short* __restrict__ Q,
    const unsigned short* __restrict__ K,
    const unsigned short* __restrict__ Vt,
    const int* __restrict__ amask,
    unsigned short* __restrict__ attn)
{
  __shared__ __align__(16) unsigned short Kl[64 * 128];
  __shared__ __align__(16) unsigned short Vl[128 * 64];
  __shared__ __align__(16) unsigned short Pl[4 * 16 * 64];  // per-wave 16x64, XOR-swizzled
  const int qt = blockIdx.x, h = blockIdx.y, b = blockIdx.z;
  const int kv = h >> 2;
  const int tid = threadIdx.x, w = tid >> 6, lane = tid & 63, quad = lane >> 4, l15 = lane & 15;
  const int q0 = qt * 64;

  bf16x8 qf[4];
  {
    const unsigned short* qbase = Q + (((size_t)(b * 2048 + q0 + w * 16 + l15)) << 12) + h * 128;
#pragma unroll
    for (int ks = 0; ks < 4; ++ks) qf[ks] = *(const bf16x8*)(qbase + ks * 32 + quad * 8);
  }
  floatx4 acco[8];
#pragma unroll
  for (int i = 0; i < 8; ++i) acco[i] = (floatx4){0.f, 0.f, 0.f, 0.f};
  float m_i[4] = {-1e30f, -1e30f, -1e30f, -1e30f};
  float l_i[4] = {0.f, 0.f, 0.f, 0.f};

  const int ts = (qt >= 16) ? (qt - 16) : 0;
  for (int jt = ts; jt <= qt; ++jt){
    const int k0 = jt * 64;
#pragma unroll
    for (int i = 0; i < 4; ++i){  // K tile: 64 rows x 256B, swizzled chunks of 16B
      int u = i * 4 + w;
      int r = u * 4 + (lane >> 4);
      int c = lane & 15;
      gl2lds16(K + (((size_t)(b * 2048 + k0 + r)) << 10) + kv * 128 + ((c ^ (r & 15)) << 3),
               (char*)Kl + u * 1024);
    }
#pragma unroll
    for (int i = 0; i < 4; ++i){  // Vt tile: 128 d-rows x 128B
      int u = i * 4 + w;
      int d = u * 8 + (lane >> 3);
      int c = lane & 7;
      gl2lds16(Vt + ((size_t)(b * 8 + kv) * 128 + d) * 2048 + k0 + ((c ^ (d & 7)) << 3),
               (char*)Vl + u * 1024);
    }
    // tile-level amask check: 64 lanes cover the 64 columns of this tile
    int mkl = amask[b * 2048 + k0 + lane];
    bool allv = (__ballot(mkl > 0) == ~0ull);
    __syncthreads();

    floatx4 accs[4];
#pragma unroll
    for (int i = 0; i < 4; ++i) accs[i] = (floatx4){0.f, 0.f, 0.f, 0.f};
#pragma unroll
    for (int ks = 0; ks < 4; ++ks)
#pragma unroll
      for (int nt = 0; nt < 4; ++nt){
        int r = nt * 16 + l15;
        int kc = ks * 4 + quad;
        bf16x8 kf = *(const bf16x8*)&Kl[r * 128 + ((kc ^ (r & 15)) << 3)];
        accs[nt] = __builtin_amdgcn_mfma_f32_16x16x32_bf16(qf[ks], kf, accs[nt], 0, 0, 0);
      }

    // Interior tiles (0 < qt-jt < 16) are provably fully inside the band:
    // j <= i since k0+63 < q0; j >= i-1024 since q0-k0 <= 960 < 961.
    bool slow = (jt == qt) || ((qt - jt) == 16) || (!allv);
    if (slow){
#pragma unroll
      for (int nt = 0; nt < 4; ++nt){
        int j = k0 + nt * 16 + l15;
        int mk = amask[b * 2048 + j];
#pragma unroll
        for (int rr = 0; rr < 4; ++rr){
          int irow = q0 + w * 16 + quad * 4 + rr;
          bool valid = (j <= irow) && (j >= irow - 1024) && (mk > 0);
          accs[nt][rr] = valid ? accs[nt][rr] : -1e30f;
        }
      }
    }

    // online softmax in exp2 domain, with defer-max (skip O-rescale when max growth <= 8)
    float vmax[4]; float need = 0.f;
#pragma unroll
    for (int rr = 0; rr < 4; ++rr){
      float v = fmaxf(fmaxf(accs[0][rr], accs[1][rr]), fmaxf(accs[2][rr], accs[3][rr]));
#pragma unroll
      for (int d_ = 1; d_ < 16; d_ <<= 1) v = fmaxf(v, __shfl_xor(v, d_));
      vmax[rr] = v;
      need = fmaxf(need, v - m_i[rr]);
    }
    if (!__all(need <= 8.0f)){
#pragma unroll
      for (int rr = 0; rr < 4; ++rr){
        float mnew = fmaxf(m_i[rr], vmax[rr]);
        float alpha = exp2f(m_i[rr] - mnew);
        m_i[rr] = mnew;
        l_i[rr] *= alpha;
#pragma unroll
        for (int n2 = 0; n2 < 8; ++n2) acco[n2][rr] *= alpha;
      }
    }
#pragma unroll
    for (int rr = 0; rr < 4; ++rr){
      float rs = 0.f;
#pragma unroll
      for (int nt = 0; nt < 4; ++nt){
        float p = exp2f(accs[nt][rr] - m_i[rr]);
        accs[nt][rr] = p;
        rs += p;
      }
#pragma unroll
      for (int d_ = 1; d_ < 16; d_ <<= 1) rs += __shfl_xor(rs, d_);
      l_i[rr] += rs;
    }
    // P (C-layout) -> LDS -> A-layout; per-wave 16x64 region, XOR-swizzled (col ^= (row&7)<<3)
#pragma unroll
    for (int nt = 0; nt < 4; ++nt)
#pragma unroll
      for (int rr = 0; rr < 4; ++rr){
        int row = quad * 4 + rr;
        Pl[w * 1024 + row * 64 + ((nt * 16 + l15) ^ ((row & 7) << 3))] = f2bf(accs[nt][rr]);
      }
#pragma unroll
    for (int ks2 = 0; ks2 < 2; ++ks2){
      bf16x8 pf = *(const bf16x8*)&Pl[w * 1024 + l15 * 64 + ((ks2 * 32 + quad * 8) ^ ((l15 & 7) << 3))];
#pragma unroll
      for (int n2 = 0; n2 < 8; ++n2){
        int d = n2 * 16 + l15;
        int sc = ks2 * 4 + quad;
        bf16x8 vf = *(const bf16x8*)&Vl[d * 64 + ((sc ^ (d & 7)) << 3)];
        acco[n2] = __builtin_amdgcn_mfma_f32_16x16x32_bf16(pf, vf, acco[n2], 0, 0, 0);
      }
    }
    __syncthreads();
  }

  float inv[4];
#pragma unroll
  for (int rr = 0; rr < 4; ++rr) inv[rr] = 1.f / l_i[rr];
#pragma unroll
  for (int n2 = 0; n2 < 8; ++n2)
#pragma unroll
    for (int rr = 0; rr < 4; ++rr){
      size_t off = (((size_t)(b * 2048 + q0 + w * 16 + quad * 4 + rr)) << 12) + h * 128 + n2 * 16 + l15;
      attn[off] = f2bf(acco[n2][rr] * inv[rr]);
    }
}

// ---------------- launch ----------------
extern "C" void kernel_launch(void* const* d_in, const int* in_sizes, int n_in,
                              void* d_out, int out_size, void* d_ws, size_t ws_size,
                              hipStream_t stream){
  const float* hidden = (const float*)d_in[0];   // [2,2048,4096] fp32
  const int* amask = (const int*)d_in[1];
  const int* pos   = (const int*)d_in[2];
  const float* qw = (const float*)d_in[3];       // [4096,4096] fp32
  const float* kw = (const float*)d_in[4];       // [4096,1024] fp32
  const float* vw = (const float*)d_in[5];       // [4096,1024] fp32
  const float* ow = (const float*)d_in[6];       // [4096,4096] fp32

  // Workspace layout — exactly 128 MiB, with liveness reuse.
  char* ws = (char*)d_ws;
  unsigned short* hb   = (unsigned short*)(ws + 0);           // hidden bf16 (32MB); dead after gemm#1 -> ot
  unsigned short* qt   = (unsigned short*)(ws + 33554432);    // q_w^T bf16 (32MB); dead after gemm#1 -> attn
  unsigned short* kt   = (unsigned short*)(ws + 67108864);    // k_w^T bf16 (8MB)
  unsigned short* vtw  = (unsigned short*)(ws + 75497472);    // v_w^T bf16 (8MB)
  unsigned short* Qb   = (unsigned short*)(ws + 83886080);    // [2,2048,32,128] (32MB)
  unsigned short* Kb   = (unsigned short*)(ws + 117440512);   // [2,2048,8,128] (8MB)
  unsigned short* Vtb  = (unsigned short*)(ws + 125829120);   // [2,8,128,2048] (8MB) -> ends at 128MiB
  unsigned short* ot   = hb;                                  // O-weight bf16^T after gemm#1
  unsigned short* attn = qt;                                  // flash output after gemm#1
  float* outp = (float*)d_out;                                // [2,2048,4096] fp32

  hipLaunchKernelGGL(conv_f32_bf16, dim3(16384), dim3(256), 0, stream, hidden, hb);
  hipLaunchKernelGGL(transpose_cvt, dim3(64, 64), dim3(256), 0, stream, qw, qt, 4096, 4096);
  hipLaunchKernelGGL(transpose_cvt, dim3(16, 64), dim3(256), 0, stream, kw, kt, 4096, 1024);
  hipLaunchKernelGGL(transpose_cvt, dim3(16, 64), dim3(256), 0, stream, vw, vtw, 4096, 1024);
  hipLaunchKernelGGL(gemm_bt, dim3(48, 32), dim3(256), 0, stream,
                     hb, qt, kt, vtw, Qb, Kb, Vtb, (float*)nullptr, 0);
  hipLaunchKernelGGL(transpose_cvt, dim3(64, 64), dim3(256), 0, stream, ow, ot, 4096, 4096); // hb dead
  hipLaunchKernelGGL(rope_apply_k, dim3(5120), dim3(256), 0, stream, Qb, Kb, pos);
  hipLaunchKernelGGL(flash_swa, dim3(32, 32, 2), dim3(256), 0, stream, Qb, Kb, Vtb, amask, attn);
  hipLaunchKernelGGL(gemm_bt, dim3(32, 32), dim3(256), 0, stream,
                     attn, ot, ot, ot, nullptr, nullptr, nullptr, outp, 1);
}

// Round 2
// 764.111 us; speedup vs baseline: 1.0394x; 1.0135x over previous
//
#include <hip/hip_runtime.h>
#include <stdint.h>
#include <stddef.h>

typedef __bf16 bf16x8 __attribute__((ext_vector_type(8)));
typedef short short8 __attribute__((ext_vector_type(8)));
typedef float floatx4 __attribute__((ext_vector_type(4)));
typedef unsigned short ushort4v __attribute__((ext_vector_type(4)));

__device__ __forceinline__ unsigned short f2bf(float f){
  unsigned int u = __float_as_uint(f);
  u += 0x7fffu + ((u >> 16) & 1u);
  return (unsigned short)(u >> 16);
}
__device__ __forceinline__ float bf2f(unsigned short s){
  return __uint_as_float(((unsigned int)s) << 16);
}
__device__ __forceinline__ void gl2lds16(const void* g, void* l){
  __builtin_amdgcn_global_load_lds((const __attribute__((address_space(1))) void*)g,
                                   (__attribute__((address_space(3))) void*)l, 16, 0, 0);
}

// ---------------- fp32 -> bf16 flat convert (n multiple of 1024) ----------------
__global__ __launch_bounds__(256) void conv_f32_bf16(const float* __restrict__ in,
                                                     unsigned short* __restrict__ out){
  int t = blockIdx.x * 256 + threadIdx.x;
  floatx4 v = *(const floatx4*)(in + (size_t)t * 4);
  ushort4v o;
#pragma unroll
  for (int j = 0; j < 4; ++j) o[j] = f2bf(v[j]);
  *(ushort4v*)(out + (size_t)t * 4) = o;
}

// ---------------- transpose+convert: fp32 [Kd,Nd] -> bf16 [Nd,Kd] ----------------
__global__ __launch_bounds__(256) void transpose_cvt(const float* __restrict__ in,
                                                     unsigned short* __restrict__ out,
                                                     int Kd, int Nd){
  __shared__ __align__(16) unsigned short tile[64 * 80];
  int n0 = blockIdx.x * 64, k0 = blockIdx.y * 64;
  int t = threadIdx.x;
#pragma unroll
  for (int it = 0; it < 2; ++it){
    int rr = (t >> 3) + it * 32;
    int cc = t & 7;
    const float* src = in + (size_t)(k0 + rr) * Nd + n0 + cc * 8;
    floatx4 a = *(const floatx4*)src;
    floatx4 b = *(const floatx4*)(src + 4);
    short8 s;
#pragma unroll
    for (int j = 0; j < 4; ++j){ s[j] = (short)f2bf(a[j]); s[j + 4] = (short)f2bf(b[j]); }
    *(short8*)&tile[rr * 80 + cc * 8] = s;
  }
  __syncthreads();
#pragma unroll
  for (int it = 0; it < 2; ++it){
    int nr = (t >> 3) + it * 32;
    int kc = t & 7;
    short8 v;
#pragma unroll
    for (int j = 0; j < 8; ++j) v[j] = (short)tile[(kc * 8 + j) * 80 + nr];
    *(short8*)(out + (size_t)(n0 + nr) * Kd + k0 + kc * 8) = v;
  }
}

// ---------------- GEMM: C[M,n] = A[M,4096] * Wt^T, Wt given as [N,4096] bf16 ----------------
// Region by n0: [0,4096) -> oQ bf16 (ld 4096) or oF fp32 if f32out; [4096,5120) -> oK; [5120,6144) -> oVt transposed.
__global__ __launch_bounds__(256, 2) void gemm_bt(
    const unsigned short* __restrict__ A,
    const unsigned short* __restrict__ Wq,
    const unsigned short* __restrict__ Wk,
    const unsigned short* __restrict__ Wv,
    unsigned short* __restrict__ oQ,
    unsigned short* __restrict__ oK,
    unsigned short* __restrict__ oVt,
    float* __restrict__ oF, int f32out)
{
  __shared__ __align__(16) unsigned short As[128 * 64];
  __shared__ __align__(16) unsigned short Bs[128 * 64];
  const int tid = threadIdx.x;
  const int w = tid >> 6, lane = tid & 63, quad = lane >> 4, l15 = lane & 15;
  const int wm64 = (w >> 1) * 64, wn64 = (w & 1) * 64;
  const int m0 = blockIdx.y * 128;
  const int n0 = blockIdx.x * 128;

  const unsigned short* Wsrc;
  int nb, region;
  if (n0 < 4096)      { Wsrc = Wq; nb = n0;        region = 0; }
  else if (n0 < 5120) { Wsrc = Wk; nb = n0 - 4096; region = 1; }
  else                { Wsrc = Wv; nb = n0 - 5120; region = 2; }

  floatx4 acc[4][4];
#pragma unroll
  for (int i = 0; i < 4; ++i)
#pragma unroll
    for (int j = 0; j < 4; ++j) acc[i][j] = (floatx4){0.f, 0.f, 0.f, 0.f};

  const int rsub = lane >> 3, csub = lane & 7;

  for (int k0 = 0; k0 < 4096; k0 += 64){
#pragma unroll
    for (int i = 0; i < 4; ++i){
      int u = i * 4 + w;
      int r = u * 8 + rsub;
      gl2lds16(A    + ((size_t)(m0 + r) << 12) + k0 + ((csub ^ (r & 7)) << 3), (char*)As + u * 1024);
      gl2lds16(Wsrc + ((size_t)(nb + r) << 12) + k0 + ((csub ^ (r & 7)) << 3), (char*)Bs + u * 1024);
    }
    __syncthreads();
#pragma unroll
    for (int ks = 0; ks < 2; ++ks){
      bf16x8 af[4], bfr[4];
#pragma unroll
      for (int mt = 0; mt < 4; ++mt){
        int r = wm64 + mt * 16 + l15;
        int kc = ks * 4 + quad;
        af[mt] = *(const bf16x8*)&As[r * 64 + ((kc ^ (r & 7)) << 3)];
      }
#pragma unroll
      for (int nt = 0; nt < 4; ++nt){
        int r = wn64 + nt * 16 + l15;
        int kc = ks * 4 + quad;
        bfr[nt] = *(const bf16x8*)&Bs[r * 64 + ((kc ^ (r & 7)) << 3)];
      }
#pragma unroll
      for (int mt = 0; mt < 4; ++mt)
#pragma unroll
        for (int nt = 0; nt < 4; ++nt)
          acc[mt][nt] = __builtin_amdgcn_mfma_f32_16x16x32_bf16(af[mt], bfr[nt], acc[mt][nt], 0, 0, 0);
    }
    __syncthreads();
  }

  if (region == 0){
    if (f32out){
#pragma unroll
      for (int mt = 0; mt < 4; ++mt)
#pragma unroll
        for (int nt = 0; nt < 4; ++nt){
          int gn = n0 + wn64 + nt * 16 + l15;
#pragma unroll
          for (int rr = 0; rr < 4; ++rr){
            int gm = m0 + wm64 + mt * 16 + quad * 4 + rr;
            oF[((size_t)gm << 12) + gn] = acc[mt][nt][rr];
          }
        }
    } else {
#pragma unroll
      for (int mt = 0; mt < 4; ++mt)
#pragma unroll
        for (int nt = 0; nt < 4; ++nt){
          int gn = n0 + wn64 + nt * 16 + l15;
#pragma unroll
          for (int rr = 0; rr < 4; ++rr){
            int gm = m0 + wm64 + mt * 16 + quad * 4 + rr;
            oQ[((size_t)gm << 12) + gn] = f2bf(acc[mt][nt][rr]);
          }
        }
    }
  } else if (region == 1){
#pragma unroll
    for (int mt = 0; mt < 4; ++mt)
#pragma unroll
      for (int nt = 0; nt < 4; ++nt){
        int gn = n0 - 4096 + wn64 + nt * 16 + l15;
#pragma unroll
        for (int rr = 0; rr < 4; ++rr){
          int gm = m0 + wm64 + mt * 16 + quad * 4 + rr;
          oK[((size_t)gm << 10) + gn] = f2bf(acc[mt][nt][rr]);
        }
      }
  } else {
#pragma unroll
    for (int mt = 0; mt < 4; ++mt){
      int gm0 = m0 + wm64 + mt * 16 + quad * 4;
      int b = gm0 >> 11, s0 = gm0 & 2047;
#pragma unroll
      for (int nt = 0; nt < 4; ++nt){
        int dg = n0 - 5120 + wn64 + nt * 16 + l15;
        int kvh = dg >> 7, d = dg & 127;
        ushort4v pk;
#pragma unroll
        for (int rr = 0; rr < 4; ++rr) pk[rr] = f2bf(acc[mt][nt][rr]);
        *(ushort4v*)(oVt + (((size_t)(b * 8 + kvh) * 128 + d) * 2048 + s0)) = pk;
      }
    }
  }
}

// ---------------- RoPE apply (in-place on Q and K), sin/cos inline ----------------
// Q additionally folded with SM_SCALE*log2(e) so attention scores land in exp2 domain.
__global__ void rope_apply_k(unsigned short* __restrict__ Qb, unsigned short* __restrict__ Kb,
                             const int* __restrict__ pos){
  int t = blockIdx.x * 256 + threadIdx.x;  // 1,310,720 total
  unsigned short* base;
  int row, ch;
  bool isq = (t < 1048576);
  if (isq){ row = t >> 8; int c = t & 255; base = Qb + ((size_t)row << 12) + (c >> 3) * 128; ch = c & 7; }
  else { int t2 = t - 1048576; row = t2 >> 6; int c = t2 & 63; base = Kb + ((size_t)row << 10) + (c >> 3) * 128; ch = c & 7; }
  float p = (float)pos[row];
  const float qs = 0.08838834764831845f * 1.44269504088896340736f; // (1/sqrt(128))*log2(e)
  float sc_out = isq ? qs : 1.0f;
  int d0 = ch * 8;
  short8 x0 = *(short8*)(base + d0);
  short8 x1 = *(short8*)(base + d0 + 64);
  short8 y0, y1;
#pragma unroll
  for (int j = 0; j < 8; ++j){
    float ang = p * exp2f(-(float)(d0 + j) * 0.20762050593045952f); // log2(1e4)/64
    float sn = sinf(ang), cs = cosf(ang);
    float a  = bf2f((unsigned short)x0[j]);
    float bb = bf2f((unsigned short)x1[j]);
    y0[j] = (short)f2bf((a * cs - bb * sn) * sc_out);
    y1[j] = (short)f2bf((bb * cs + a * sn) * sc_out);
  }
  *(short8*)(base + d0)      = y0;
  *(short8*)(base + d0 + 64) = y1;
}

// ---------------- flash attention, sliding window 1024 ----------------
// grid (32 qtiles, 32 heads, 2 batch); block 256 = 4 waves; 16 q rows/wave.
// Scores arrive pre-scaled to exp2 domain (SM_SCALE*log2e folded into Q).
// T3 minimal 2-phase pipeline: double-buffered K/V in LDS; next tile's
// global_load_lds issued BEFORE compute on current tile; ONE barrier per tile
// (its vmcnt(0) drain lands on loads that have had the whole compute phase to
// complete). amask ballot hoisted to a single conservative whole-row check.
__global__ __launch_bounds__(256, 2) void flash_swa(
    const unsigned short* __restrict__ Q,
    const unsigned short* __restrict__ K,
    const unsigned short* __restrict__ Vt,
    const int* __restrict__ amask,
    unsigned short* __restrict__ attn)
{
  __shared__ __align__(16) unsigned short Kl[2][64 * 128];
  __shared__ __align__(16) unsigned short Vl[2][128 * 64];
  __shared__ __align__(16) unsigned short Pl[4 * 16 * 64];  // per-wave 16x64, XOR-swizzled
  const int qt = blockIdx.x, h = blockIdx.y, b = blockIdx.z;
  const int kv = h >> 2;
  const int tid = threadIdx.x, w = tid >> 6, lane = tid & 63, quad = lane >> 4, l15 = lane & 15;
  const int q0 = qt * 64;

  // Whole-sequence amask check (conservative): if any position is masked,
  // every tile takes the slow path. Benchmark mask is all-ones -> fast path.
  bool anybad = false;
  {
    const int* ap = amask + b * 2048 + lane * 32;
#pragma unroll
    for (int i = 0; i < 8; ++i){
      int4 mv = *(const int4*)(ap + i * 4);
      anybad |= (mv.x <= 0) | (mv.y <= 0) | (mv.z <= 0) | (mv.w <= 0);
    }
  }
  const bool allv = (__ballot(anybad) == 0ull);

  bf16x8 qf[4];
  {
    const unsigned short* qbase = Q + (((size_t)(b * 2048 + q0 + w * 16 + l15)) << 12) + h * 128;
#pragma unroll
    for (int ks = 0; ks < 4; ++ks) qf[ks] = *(const bf16x8*)(qbase + ks * 32 + quad * 8);
  }
  floatx4 acco[8];
#pragma unroll
  for (int i = 0; i < 8; ++i) acco[i] = (floatx4){0.f, 0.f, 0.f, 0.f};
  float m_i[4] = {-1e30f, -1e30f, -1e30f, -1e30f};
  float l_i[4] = {0.f, 0.f, 0.f, 0.f};

  const int ts = (qt >= 16) ? (qt - 16) : 0;

  // ---- stage helper (K tile: 64 rows x 256B; Vt tile: 128 d-rows x 128B) ----
#define STAGE_KV(JT, BUF)                                                                  \
  {                                                                                        \
    const int k0s = (JT) * 64;                                                             \
    _Pragma("unroll")                                                                      \
    for (int i_ = 0; i_ < 4; ++i_){                                                        \
      int u_ = i_ * 4 + w;                                                                 \
      int r_ = u_ * 4 + (lane >> 4);                                                       \
      int c_ = lane & 15;                                                                  \
      gl2lds16(K + (((size_t)(b * 2048 + k0s + r_)) << 10) + kv * 128 + ((c_ ^ (r_ & 15)) << 3), \
               (char*)Kl[BUF] + u_ * 1024);                                                \
    }                                                                                      \
    _Pragma("unroll")                                                                      \
    for (int i_ = 0; i_ < 4; ++i_){                                                        \
      int u_ = i_ * 4 + w;                                                                 \
      int d_ = u_ * 8 + (lane >> 3);                                                       \
      int c_ = lane & 7;                                                                   \
      gl2lds16(Vt + ((size_t)(b * 8 + kv) * 128 + d_) * 2048 + k0s + ((c_ ^ (d_ & 7)) << 3), \
               (char*)Vl[BUF] + u_ * 1024);                                                \
    }                                                                                      \
  }

  // prologue: fill buffer 0
  STAGE_KV(ts, 0);
  __syncthreads();

  int cur = 0;
  for (int jt = ts; jt <= qt; ++jt){
    const int k0 = jt * 64;
    // prefetch next tile into the other buffer (hidden under this tile's compute)
    if (jt < qt) STAGE_KV(jt + 1, cur ^ 1);

    const unsigned short* Klc = Kl[cur];
    const unsigned short* Vlc = Vl[cur];

    floatx4 accs[4];
#pragma unroll
    for (int i = 0; i < 4; ++i) accs[i] = (floatx4){0.f, 0.f, 0.f, 0.f};
    __builtin_amdgcn_s_setprio(1);
#pragma unroll
    for (int ks = 0; ks < 4; ++ks)
#pragma unroll
      for (int nt = 0; nt < 4; ++nt){
        int r = nt * 16 + l15;
        int kc = ks * 4 + quad;
        bf16x8 kf = *(const bf16x8*)&Klc[r * 128 + ((kc ^ (r & 15)) << 3)];
        accs[nt] = __builtin_amdgcn_mfma_f32_16x16x32_bf16(qf[ks], kf, accs[nt], 0, 0, 0);
      }
    __builtin_amdgcn_s_setprio(0);

    // Interior tiles (0 < qt-jt < 16) are provably fully inside the band:
    // j <= i since k0+63 < q0; j >= i-1024 since q0-k0 <= 960 < 961.
    bool slow = (jt == qt) || ((qt - jt) == 16) || (!allv);
    if (slow){
#pragma unroll
      for (int nt = 0; nt < 4; ++nt){
        int j = k0 + nt * 16 + l15;
        int mk = amask[b * 2048 + j];
#pragma unroll
        for (int rr = 0; rr < 4; ++rr){
          int irow = q0 + w * 16 + quad * 4 + rr;
          bool valid = (j <= irow) && (j >= irow - 1024) && (mk > 0);
          accs[nt][rr] = valid ? accs[nt][rr] : -1e30f;
        }
      }
    }

    // online softmax in exp2 domain, with defer-max (skip O-rescale when max growth <= 8)
    float vmax[4]; float need = 0.f;
#pragma unroll
    for (int rr = 0; rr < 4; ++rr){
      float v = fmaxf(fmaxf(accs[0][rr], accs[1][rr]), fmaxf(accs[2][rr], accs[3][rr]));
#pragma unroll
      for (int d_ = 1; d_ < 16; d_ <<= 1) v = fmaxf(v, __shfl_xor(v, d_));
      vmax[rr] = v;
      need = fmaxf(need, v - m_i[rr]);
    }
    if (!__all(need <= 8.0f)){
#pragma unroll
      for (int rr = 0; rr < 4; ++rr){
        float mnew = fmaxf(m_i[rr], vmax[rr]);
        float alpha = exp2f(m_i[rr] - mnew);
        m_i[rr] = mnew;
        l_i[rr] *= alpha;
#pragma unroll
        for (int n2 = 0; n2 < 8; ++n2) acco[n2][rr] *= alpha;
      }
    }
#pragma unroll
    for (int rr = 0; rr < 4; ++rr){
      float rs = 0.f;
#pragma unroll
      for (int nt = 0; nt < 4; ++nt){
        float p = exp2f(accs[nt][rr] - m_i[rr]);
        accs[nt][rr] = p;
        rs += p;
      }
#pragma unroll
      for (int d_ = 1; d_ < 16; d_ <<= 1) rs += __shfl_xor(rs, d_);
      l_i[rr] += rs;
    }
    // P (C-layout) -> LDS -> A-layout; per-wave 16x64 region, XOR-swizzled (col ^= (row&7)<<3)
#pragma unroll
    for (int nt = 0; nt < 4; ++nt)
#pragma unroll
      for (int rr = 0; rr < 4; ++rr){
        int row = quad * 4 + rr;
        Pl[w * 1024 + row * 64 + ((nt * 16 + l15) ^ ((row & 7) << 3))] = f2bf(accs[nt][rr]);
      }
    __builtin_amdgcn_s_setprio(1);
#pragma unroll
    for (int ks2 = 0; ks2 < 2; ++ks2){
      bf16x8 pf = *(const bf16x8*)&Pl[w * 1024 + l15 * 64 + ((ks2 * 32 + quad * 8) ^ ((l15 & 7) << 3))];
#pragma unroll
      for (int n2 = 0; n2 < 8; ++n2){
        int d = n2 * 16 + l15;
        int sc = ks2 * 4 + quad;
        bf16x8 vf = *(const bf16x8*)&Vlc[d * 64 + ((sc ^ (d & 7)) << 3)];
        acco[n2] = __builtin_amdgcn_mfma_f32_16x16x32_bf16(pf, vf, acco[n2], 0, 0, 0);
      }
    }
    __builtin_amdgcn_s_setprio(0);
    // single barrier per tile: drains the prefetch (long since issued) and
    // protects buffer cur^1 reads (done 2 iters ago) from being overwritten.
    __syncthreads();
    cur ^= 1;
  }
#undef STAGE_KV

  float inv[4];
#pragma unroll
  for (int rr = 0; rr < 4; ++rr) inv[rr] = 1.f / l_i[rr];
#pragma unroll
  for (int n2 = 0; n2 < 8; ++n2)
#pragma unroll
    for (int rr = 0; rr < 4; ++rr){
      size_t off = (((size_t)(b * 2048 + q0 + w * 16 + quad * 4 + rr)) << 12) + h * 128 + n2 * 16 + l15;
      attn[off] = f2bf(acco[n2][rr] * inv[rr]);
    }
}

// ---------------- launch ----------------
extern "C" void kernel_launch(void* const* d_in, const int* in_sizes, int n_in,
                              void* d_out, int out_size, void* d_ws, size_t ws_size,
                              hipStream_t stream){
  const float* hidden = (const float*)d_in[0];   // [2,2048,4096] fp32
  const int* amask = (const int*)d_in[1];
  const int* pos   = (const int*)d_in[2];
  const float* qw = (const float*)d_in[3];       // [4096,4096] fp32
  const float* kw = (const float*)d_in[4];       // [4096,1024] fp32
  const float* vw = (const float*)d_in[5];       // [4096,1024] fp32
  const float* ow = (const float*)d_in[6];       // [4096,4096] fp32

  // Workspace layout — exactly 128 MiB, with liveness reuse.
  char* ws = (char*)d_ws;
  unsigned short* hb   = (unsigned short*)(ws + 0);           // hidden bf16 (32MB); dead after gemm#1 -> ot
  unsigned short* qt   = (unsigned short*)(ws + 33554432);    // q_w^T bf16 (32MB); dead after gemm#1 -> attn
  unsigned short* kt   = (unsigned short*)(ws + 67108864);    // k_w^T bf16 (8MB)
  unsigned short* vtw  = (unsigned short*)(ws + 75497472);    // v_w^T bf16 (8MB)
  unsigned short* Qb   = (unsigned short*)(ws + 83886080);    // [2,2048,32,128] (32MB)
  unsigned short* Kb   = (unsigned short*)(ws + 117440512);   // [2,2048,8,128] (8MB)
  unsigned short* Vtb  = (unsigned short*)(ws + 125829120);   // [2,8,128,2048] (8MB) -> ends at 128MiB
  unsigned short* ot   = hb;                                  // O-weight bf16^T after gemm#1
  unsigned short* attn = qt;                                  // flash output after gemm#1
  float* outp = (float*)d_out;                                // [2,2048,4096] fp32

  hipLaunchKernelGGL(conv_f32_bf16, dim3(16384), dim3(256), 0, stream, hidden, hb);
  hipLaunchKernelGGL(transpose_cvt, dim3(64, 64), dim3(256), 0, stream, qw, qt, 4096, 4096);
  hipLaunchKernelGGL(transpose_cvt, dim3(16, 64), dim3(256), 0, stream, kw, kt, 4096, 1024);
  hipLaunchKernelGGL(transpose_cvt, dim3(16, 64), dim3(256), 0, stream, vw, vtw, 4096, 1024);
  hipLaunchKernelGGL(gemm_bt, dim3(48, 32), dim3(256), 0, stream,
                     hb, qt, kt, vtw, Qb, Kb, Vtb, (float*)nullptr, 0);
  hipLaunchKernelGGL(transpose_cvt, dim3(64, 64), dim3(256), 0, stream, ow, ot, 4096, 4096); // hb dead
  hipLaunchKernelGGL(rope_apply_k, dim3(5120), dim3(256), 0, stream, Qb, Kb, pos);
  hipLaunchKernelGGL(flash_swa, dim3(32, 32, 2), dim3(256), 0, stream, Qb, Kb, Vtb, amask, attn);
  hipLaunchKernelGGL(gemm_bt, dim3(32, 32), dim3(256), 0, stream,
                     attn, ot, ot, ot, nullptr, nullptr, nullptr, outp, 1);
}

// Round 4
// 698.849 us; speedup vs baseline: 1.1365x; 1.0934x over previous
//
#include <hip/hip_runtime.h>
#include <stdint.h>
#include <stddef.h>

typedef __bf16 bf16x8 __attribute__((ext_vector_type(8)));
typedef short short8 __attribute__((ext_vector_type(8)));
typedef float floatx4 __attribute__((ext_vector_type(4)));
typedef float f32x16 __attribute__((ext_vector_type(16)));
typedef unsigned short ushort4v __attribute__((ext_vector_type(4)));
typedef unsigned int uint2v __attribute__((ext_vector_type(2)));

__device__ __forceinline__ unsigned short f2bf(float f){
  unsigned int u = __float_as_uint(f);
  u += 0x7fffu + ((u >> 16) & 1u);
  return (unsigned short)(u >> 16);
}
__device__ __forceinline__ float bf2f(unsigned short s){
  return __uint_as_float(((unsigned int)s) << 16);
}
__device__ __forceinline__ void gl2lds16(const void* g, void* l){
  __builtin_amdgcn_global_load_lds((const __attribute__((address_space(1))) void*)g,
                                   (__attribute__((address_space(3))) void*)l, 16, 0, 0);
}

// ---------------- fp32 -> bf16 flat convert (n multiple of 1024) ----------------
__global__ __launch_bounds__(256) void conv_f32_bf16(const float* __restrict__ in,
                                                     unsigned short* __restrict__ out){
  int t = blockIdx.x * 256 + threadIdx.x;
  floatx4 v = *(const floatx4*)(in + (size_t)t * 4);
  ushort4v o;
#pragma unroll
  for (int j = 0; j < 4; ++j) o[j] = f2bf(v[j]);
  *(ushort4v*)(out + (size_t)t * 4) = o;
}

// ---------------- transpose+convert: fp32 [Kd,Nd] -> bf16 [Nd,Kd] ----------------
__global__ __launch_bounds__(256) void transpose_cvt(const float* __restrict__ in,
                                                     unsigned short* __restrict__ out,
                                                     int Kd, int Nd){
  __shared__ __align__(16) unsigned short tile[64 * 80];
  int n0 = blockIdx.x * 64, k0 = blockIdx.y * 64;
  int t = threadIdx.x;
#pragma unroll
  for (int it = 0; it < 2; ++it){
    int rr = (t >> 3) + it * 32;
    int cc = t & 7;
    const float* src = in + (size_t)(k0 + rr) * Nd + n0 + cc * 8;
    floatx4 a = *(const floatx4*)src;
    floatx4 b = *(const floatx4*)(src + 4);
    short8 s;
#pragma unroll
    for (int j = 0; j < 4; ++j){ s[j] = (short)f2bf(a[j]); s[j + 4] = (short)f2bf(b[j]); }
    *(short8*)&tile[rr * 80 + cc * 8] = s;
  }
  __syncthreads();
#pragma unroll
  for (int it = 0; it < 2; ++it){
    int nr = (t >> 3) + it * 32;
    int kc = t & 7;
    short8 v;
#pragma unroll
    for (int j = 0; j < 8; ++j) v[j] = (short)tile[(kc * 8 + j) * 80 + nr];
    *(short8*)(out + (size_t)(n0 + nr) * Kd + k0 + kc * 8) = v;
  }
}

// ---------------- GEMM: C[M,n] = A[M,4096] * Wt^T, Wt given as [N,4096] bf16 ----------------
__global__ __launch_bounds__(256, 2) void gemm_bt(
    const unsigned short* __restrict__ A,
    const unsigned short* __restrict__ Wq,
    const unsigned short* __restrict__ Wk,
    const unsigned short* __restrict__ Wv,
    unsigned short* __restrict__ oQ,
    unsigned short* __restrict__ oK,
    unsigned short* __restrict__ oVt,
    float* __restrict__ oF, int f32out)
{
  __shared__ __align__(16) unsigned short As[128 * 64];
  __shared__ __align__(16) unsigned short Bs[128 * 64];
  const int tid = threadIdx.x;
  const int w = tid >> 6, lane = tid & 63, quad = lane >> 4, l15 = lane & 15;
  const int wm64 = (w >> 1) * 64, wn64 = (w & 1) * 64;
  const int m0 = blockIdx.y * 128;
  const int n0 = blockIdx.x * 128;

  const unsigned short* Wsrc;
  int nb, region;
  if (n0 < 4096)      { Wsrc = Wq; nb = n0;        region = 0; }
  else if (n0 < 5120) { Wsrc = Wk; nb = n0 - 4096; region = 1; }
  else                { Wsrc = Wv; nb = n0 - 5120; region = 2; }

  floatx4 acc[4][4];
#pragma unroll
  for (int i = 0; i < 4; ++i)
#pragma unroll
    for (int j = 0; j < 4; ++j) acc[i][j] = (floatx4){0.f, 0.f, 0.f, 0.f};

  const int rsub = lane >> 3, csub = lane & 7;

  for (int k0 = 0; k0 < 4096; k0 += 64){
#pragma unroll
    for (int i = 0; i < 4; ++i){
      int u = i * 4 + w;
      int r = u * 8 + rsub;
      gl2lds16(A    + ((size_t)(m0 + r) << 12) + k0 + ((csub ^ (r & 7)) << 3), (char*)As + u * 1024);
      gl2lds16(Wsrc + ((size_t)(nb + r) << 12) + k0 + ((csub ^ (r & 7)) << 3), (char*)Bs + u * 1024);
    }
    __syncthreads();
#pragma unroll
    for (int ks = 0; ks < 2; ++ks){
      bf16x8 af[4], bfr[4];
#pragma unroll
      for (int mt = 0; mt < 4; ++mt){
        int r = wm64 + mt * 16 + l15;
        int kc = ks * 4 + quad;
        af[mt] = *(const bf16x8*)&As[r * 64 + ((kc ^ (r & 7)) << 3)];
      }
#pragma unroll
      for (int nt = 0; nt < 4; ++nt){
        int r = wn64 + nt * 16 + l15;
        int kc = ks * 4 + quad;
        bfr[nt] = *(const bf16x8*)&Bs[r * 64 + ((kc ^ (r & 7)) << 3)];
      }
#pragma unroll
      for (int mt = 0; mt < 4; ++mt)
#pragma unroll
        for (int nt = 0; nt < 4; ++nt)
          acc[mt][nt] = __builtin_amdgcn_mfma_f32_16x16x32_bf16(af[mt], bfr[nt], acc[mt][nt], 0, 0, 0);
    }
    __syncthreads();
  }

  if (region == 0){
    if (f32out){
#pragma unroll
      for (int mt = 0; mt < 4; ++mt)
#pragma unroll
        for (int nt = 0; nt < 4; ++nt){
          int gn = n0 + wn64 + nt * 16 + l15;
#pragma unroll
          for (int rr = 0; rr < 4; ++rr){
            int gm = m0 + wm64 + mt * 16 + quad * 4 + rr;
            oF[((size_t)gm << 12) + gn] = acc[mt][nt][rr];
          }
        }
    } else {
#pragma unroll
      for (int mt = 0; mt < 4; ++mt)
#pragma unroll
        for (int nt = 0; nt < 4; ++nt){
          int gn = n0 + wn64 + nt * 16 + l15;
#pragma unroll
          for (int rr = 0; rr < 4; ++rr){
            int gm = m0 + wm64 + mt * 16 + quad * 4 + rr;
            oQ[((size_t)gm << 12) + gn] = f2bf(acc[mt][nt][rr]);
          }
        }
    }
  } else if (region == 1){
#pragma unroll
    for (int mt = 0; mt < 4; ++mt)
#pragma unroll
      for (int nt = 0; nt < 4; ++nt){
        int gn = n0 - 4096 + wn64 + nt * 16 + l15;
#pragma unroll
        for (int rr = 0; rr < 4; ++rr){
          int gm = m0 + wm64 + mt * 16 + quad * 4 + rr;
          oK[((size_t)gm << 10) + gn] = f2bf(acc[mt][nt][rr]);
        }
      }
  } else {
#pragma unroll
    for (int mt = 0; mt < 4; ++mt){
      int gm0 = m0 + wm64 + mt * 16 + quad * 4;
      int b = gm0 >> 11, s0 = gm0 & 2047;
#pragma unroll
      for (int nt = 0; nt < 4; ++nt){
        int dg = n0 - 5120 + wn64 + nt * 16 + l15;
        int kvh = dg >> 7, d = dg & 127;
        ushort4v pk;
#pragma unroll
        for (int rr = 0; rr < 4; ++rr) pk[rr] = f2bf(acc[mt][nt][rr]);
        *(ushort4v*)(oVt + (((size_t)(b * 8 + kvh) * 128 + d) * 2048 + s0)) = pk;
      }
    }
  }
}

// ---------------- RoPE apply (in-place on Q and K), sin/cos inline ----------------
// Q additionally folded with SM_SCALE*log2(e) so attention scores land in exp2 domain.
__global__ void rope_apply_k(unsigned short* __restrict__ Qb, unsigned short* __restrict__ Kb,
                             const int* __restrict__ pos){
  int t = blockIdx.x * 256 + threadIdx.x;  // 1,310,720 total
  unsigned short* base;
  int row, ch;
  bool isq = (t < 1048576);
  if (isq){ row = t >> 8; int c = t & 255; base = Qb + ((size_t)row << 12) + (c >> 3) * 128; ch = c & 7; }
  else { int t2 = t - 1048576; row = t2 >> 6; int c = t2 & 63; base = Kb + ((size_t)row << 10) + (c >> 3) * 128; ch = c & 7; }
  float p = (float)pos[row];
  const float qs = 0.08838834764831845f * 1.44269504088896340736f; // (1/sqrt(128))*log2(e)
  float sc_out = isq ? qs : 1.0f;
  int d0 = ch * 8;
  short8 x0 = *(short8*)(base + d0);
  short8 x1 = *(short8*)(base + d0 + 64);
  short8 y0, y1;
#pragma unroll
  for (int j = 0; j < 8; ++j){
    float ang = p * exp2f(-(float)(d0 + j) * 0.20762050593045952f); // log2(1e4)/64
    float sn = sinf(ang), cs = cosf(ang);
    float a  = bf2f((unsigned short)x0[j]);
    float bb = bf2f((unsigned short)x1[j]);
    y0[j] = (short)f2bf((a * cs - bb * sn) * sc_out);
    y1[j] = (short)f2bf((bb * cs + a * sn) * sc_out);
  }
  *(short8*)(base + d0)      = y0;
  *(short8*)(base + d0 + 64) = y1;
}

// ---------------- flash attention, sliding window 1024 ----------------
// Swapped-QK 32x32 structure: 4 warps x 32 q-rows = 128 rows/block.
// grid (16 qtiles, 32 heads, 2 batch); block 256 = 4 waves.
// Per tile: S^T = mfma(K,Q) -> each lane owns 32 P^T values for col q=lane&31.
// Row softmax in-register (tree + __shfl_xor(.,32) cross-half combine).
// P -> bf16 B-frags via per-warp LDS round trip ([q][kpair] u32, chunk-XOR swizzle).
// PV: O^T = mfma(V^T, P) -> acco col = q = lane&31 (per-lane alpha/inv trivial).
// Epilogue: per-warp LDS transpose (reuses Kl) -> coalesced 16B stores.
__global__ __launch_bounds__(256, 2) void flash_swa(
    const unsigned short* __restrict__ Q,
    const unsigned short* __restrict__ K,
    const unsigned short* __restrict__ Vt,
    const int* __restrict__ amask,
    unsigned short* __restrict__ attn)
{
  __shared__ __align__(16) unsigned short Kl[2][64 * 128];   // 32 KB
  __shared__ __align__(16) unsigned short Vl[2][128 * 64];   // 32 KB
  __shared__ __align__(16) unsigned int   Pl[4][1024];       // 16 KB: per-warp [q=32][kpair=32]
  const int h = blockIdx.y, b = blockIdx.z;
  const int kv = h >> 2;
  const int tid = threadIdx.x, w = tid >> 6, lane = tid & 63;
  const int l31 = lane & 31, hi = lane >> 5, hi4 = hi << 2;
  const int qb = blockIdx.x * 128;
  const int t0 = qb >> 6;                 // 64-tile index of block start
  const int qw0 = qb + w * 32;            // this warp's first q row
  const int aw = t0 + (w >> 1);           // this warp's diagonal 64-tile

  // Whole-sequence amask check (conservative): bench mask is all-ones -> fast path.
  bool anybad = false;
  {
    const int* ap = amask + b * 2048 + lane * 32;
#pragma unroll
    for (int i = 0; i < 8; ++i){
      int4 mv = *(const int4*)(ap + i * 4);
      anybad |= (mv.x <= 0) | (mv.y <= 0) | (mv.z <= 0) | (mv.w <= 0);
    }
  }
  const bool allv = (__ballot(anybad) == 0ull);

  // Q fragments (B-operand of swapped QK): lane holds col q=l31, k-slice hi*8+j
  bf16x8 qf[8];
  {
    const unsigned short* qbase = Q + (((size_t)(b * 2048 + qw0 + l31)) << 12) + h * 128;
#pragma unroll
    for (int ds = 0; ds < 8; ++ds) qf[ds] = *(const bf16x8*)(qbase + ds * 16 + hi * 8);
  }

  f32x16 acco[4];
#pragma unroll
  for (int i = 0; i < 4; ++i)
#pragma unroll
    for (int j = 0; j < 16; ++j) acco[i][j] = 0.f;
  float m_i = -1e30f, l_i = 0.f;

  const int jb0 = (t0 >= 16) ? (t0 - 16) : 0;
  const int jtend = t0 + 1;

#define STAGE_KV(JT, BUF)                                                                  \
  {                                                                                        \
    const int k0s = (JT) * 64;                                                             \
    _Pragma("unroll")                                                                      \
    for (int i_ = 0; i_ < 4; ++i_){                                                        \
      int u_ = i_ * 4 + w;                                                                 \
      int r_ = u_ * 4 + (lane >> 4);                                                       \
      int c_ = lane & 15;                                                                  \
      gl2lds16(K + (((size_t)(b * 2048 + k0s + r_)) << 10) + kv * 128 + ((c_ ^ (r_ & 15)) << 3), \
               (char*)Kl[BUF] + u_ * 1024);                                                \
    }                                                                                      \
    _Pragma("unroll")                                                                      \
    for (int i_ = 0; i_ < 4; ++i_){                                                        \
      int u_ = i_ * 4 + w;                                                                 \
      int d_ = u_ * 8 + (lane >> 3);                                                       \
      int c_ = lane & 7;                                                                   \
      gl2lds16(Vt + ((size_t)(b * 8 + kv) * 128 + d_) * 2048 + k0s + ((c_ ^ (d_ & 7)) << 3), \
               (char*)Vl[BUF] + u_ * 1024);                                                \
    }                                                                                      \
  }

  STAGE_KV(jb0, 0);
  __syncthreads();

  unsigned int* Pw = &Pl[w][0];
  int cur = 0;
  for (int jt = jb0; jt <= jtend; ++jt){
    if (jt < jtend) STAGE_KV(jt + 1, cur ^ 1);

    const bool active = (jt >= aw - 16) && (jt <= aw);
    if (active){
      const int k0 = jt * 64;
      const unsigned short* Klc = Kl[cur];
      const unsigned short* Vlc = Vl[cur];

      // ---- QK^T (swapped): ps[kb] = S^T block, rows k = kb*32 + crow, cols q ----
      f32x16 ps[2];
#pragma unroll
      for (int kb = 0; kb < 2; ++kb)
#pragma unroll
        for (int j = 0; j < 16; ++j) ps[kb][j] = 0.f;

      __builtin_amdgcn_s_setprio(1);
#pragma unroll
      for (int ds = 0; ds < 8; ++ds){
#pragma unroll
        for (int kb = 0; kb < 2; ++kb){
          int r = kb * 32 + l31;
          bf16x8 kf = *(const bf16x8*)&Klc[r * 128 + (((ds * 2 + hi) ^ (r & 15)) << 3)];
          ps[kb] = __builtin_amdgcn_mfma_f32_32x32x16_bf16(kf, qf[ds], ps[kb], 0, 0, 0);
        }
      }
      __builtin_amdgcn_s_setprio(0);

      // ---- masking: only diagonal / window-edge tiles (or masked sequences) ----
      const bool slow = (jt == aw) || (jt == aw - 16) || (!allv);
      if (slow){
        unsigned long long mb = __ballot(amask[b * 2048 + k0 + lane] > 0);
        int irow = qw0 + l31;
#pragma unroll
        for (int kb = 0; kb < 2; ++kb)
#pragma unroll
          for (int reg = 0; reg < 16; ++reg){
            int jv = k0 + kb * 32 + (reg & 3) + 8 * (reg >> 2) + hi4;
            bool valid = (jv <= irow) && (jv >= irow - 1024) &&
                         (((mb >> (jv & 63)) & 1ull) != 0ull);
            ps[kb][reg] = valid ? ps[kb][reg] : -1e30f;
          }
      }

      // ---- in-register online softmax (exp2 domain, defer-max THR=8) ----
      float t16[16];
#pragma unroll
      for (int r = 0; r < 16; ++r) t16[r] = fmaxf(ps[0][r], ps[1][r]);
      float t8[8];
#pragma unroll
      for (int r = 0; r < 8; ++r) t8[r] = fmaxf(t16[r], t16[r + 8]);
      float t4[4];
#pragma unroll
      for (int r = 0; r < 4; ++r) t4[r] = fmaxf(t8[r], t8[r + 4]);
      float vm = fmaxf(fmaxf(t4[0], t4[1]), fmaxf(t4[2], t4[3]));
      float vmax = fmaxf(vm, __shfl_xor(vm, 32));

      if (!__all(vmax - m_i <= 8.0f)){
        float mnew = fmaxf(m_i, vmax);
        float alpha = exp2f(m_i - mnew);
        m_i = mnew;
        l_i *= alpha;
#pragma unroll
        for (int db = 0; db < 4; ++db) acco[db] *= alpha;
      }

#pragma unroll
      for (int kb = 0; kb < 2; ++kb)
#pragma unroll
        for (int reg = 0; reg < 16; ++reg) ps[kb][reg] = exp2f(ps[kb][reg] - m_i);

      float s16[16];
#pragma unroll
      for (int r = 0; r < 16; ++r) s16[r] = ps[0][r] + ps[1][r];
      float s8[8];
#pragma unroll
      for (int r = 0; r < 8; ++r) s8[r] = s16[r] + s16[r + 8];
      float s4[4];
#pragma unroll
      for (int r = 0; r < 4; ++r) s4[r] = s8[r] + s8[r + 4];
      float sm = (s4[0] + s4[1]) + (s4[2] + s4[3]);
      l_i += sm + __shfl_xor(sm, 32);

      // ---- P -> LDS ([q][kpair] u32, 16B-chunk XOR swizzle), then read B-frags ----
      // k (in tile) = kb*32 + (reg&3) + 8*(reg>>2) + 4*hi ; kpair = k>>1.
      // write: regs (4g+0,4g+1) -> kpair kb*16+4g+2hi ; (4g+2,4g+3) -> +1 (one b64).
#pragma unroll
      for (int kb = 0; kb < 2; ++kb)
#pragma unroll
        for (int g = 0; g < 4; ++g){
          unsigned p0 = (unsigned)f2bf(ps[kb][g * 4 + 0]) | ((unsigned)f2bf(ps[kb][g * 4 + 1]) << 16);
          unsigned p1 = (unsigned)f2bf(ps[kb][g * 4 + 2]) | ((unsigned)f2bf(ps[kb][g * 4 + 3]) << 16);
          int ch = (kb * 4 + g) ^ (l31 & 7);
          uint2v pv_; pv_[0] = p0; pv_[1] = p1;
          *(uint2v*)&Pw[l31 * 32 + ch * 4 + hi * 2] = pv_;
        }
      // read: pa[ks] = k = ks*16 + hi*8 + (0..7)  -> chunk 2ks+hi, one b128.
      bf16x8 pa[4];
#pragma unroll
      for (int ks = 0; ks < 4; ++ks)
        pa[ks] = *(const bf16x8*)&Pw[l31 * 32 + (((ks * 2 + hi) ^ (l31 & 7)) << 2)];

      // ---- PV: acco[db] (O^T block) += mfma(V^T frag, P frag) ----
      __builtin_amdgcn_s_setprio(1);
#pragma unroll
      for (int ks = 0; ks < 4; ++ks){
#pragma unroll
        for (int db = 0; db < 4; ++db){
          int d = db * 32 + l31;
          bf16x8 vf = *(const bf16x8*)&Vlc[d * 64 + (((ks * 2 + hi) ^ (d & 7)) << 3)];
          acco[db] = __builtin_amdgcn_mfma_f32_32x32x16_bf16(vf, pa[ks], acco[db], 0, 0, 0);
        }
      }
      __builtin_amdgcn_s_setprio(0);
    }

    __syncthreads();
    cur ^= 1;
  }
#undef STAGE_KV

  // ---- epilogue: per-warp LDS transpose (reuse Kl area), coalesced stores ----
  float invl = 1.f / l_i;
  unsigned short* Ep = ((unsigned short*)Kl) + w * 4096;  // 32 q-rows x 128 d, XOR-swizzled
  {
    const int q = l31;
#pragma unroll
    for (int db = 0; db < 4; ++db)
#pragma unroll
      for (int reg = 0; reg < 16; ++reg){
        int dc = db * 4 + (reg >> 2);          // d>>3
        int dl = (reg & 3) + hi4;              // d&7
        Ep[q * 128 + ((dc ^ (q & 15)) << 3) + dl] = f2bf(acco[db][reg] * invl);
      }
  }
  {
    const int rr_ = lane >> 4, cc = lane & 15;
#pragma unroll
    for (int p8 = 0; p8 < 8; ++p8){
      int q = p8 * 4 + rr_;
      short8 vv = *(const short8*)&Ep[q * 128 + ((cc ^ (q & 15)) << 3)];
      size_t off = (((size_t)(b * 2048 + qb + w * 32 + q)) << 12) + h * 128 + cc * 8;
      *(short8*)(attn + off) = vv;
    }
  }
}

// ---------------- launch ----------------
extern "C" void kernel_launch(void* const* d_in, const int* in_sizes, int n_in,
                              void* d_out, int out_size, void* d_ws, size_t ws_size,
                              hipStream_t stream){
  const float* hidden = (const float*)d_in[0];   // [2,2048,4096] fp32
  const int* amask = (const int*)d_in[1];
  const int* pos   = (const int*)d_in[2];
  const float* qw = (const float*)d_in[3];       // [4096,4096] fp32
  const float* kw = (const float*)d_in[4];       // [4096,1024] fp32
  const float* vw = (const float*)d_in[5];       // [4096,1024] fp32
  const float* ow = (const float*)d_in[6];       // [4096,4096] fp32

  // Workspace layout — exactly 128 MiB, with liveness reuse.
  char* ws = (char*)d_ws;
  unsigned short* hb   = (unsigned short*)(ws + 0);           // hidden bf16 (32MB); dead after gemm#1 -> ot
  unsigned short* qt   = (unsigned short*)(ws + 33554432);    // q_w^T bf16 (32MB); dead after gemm#1 -> attn
  unsigned short* kt   = (unsigned short*)(ws + 67108864);    // k_w^T bf16 (8MB)
  unsigned short* vtw  = (unsigned short*)(ws + 75497472);    // v_w^T bf16 (8MB)
  unsigned short* Qb   = (unsigned short*)(ws + 83886080);    // [2,2048,32,128] (32MB)
  unsigned short* Kb   = (unsigned short*)(ws + 117440512);   // [2,2048,8,128] (8MB)
  unsigned short* Vtb  = (unsigned short*)(ws + 125829120);   // [2,8,128,2048] (8MB) -> ends at 128MiB
  unsigned short* ot   = hb;                                  // O-weight bf16^T after gemm#1
  unsigned short* attn = qt;                                  // flash output after gemm#1
  float* outp = (float*)d_out;                                // [2,2048,4096] fp32

  hipLaunchKernelGGL(conv_f32_bf16, dim3(16384), dim3(256), 0, stream, hidden, hb);
  hipLaunchKernelGGL(transpose_cvt, dim3(64, 64), dim3(256), 0, stream, qw, qt, 4096, 4096);
  hipLaunchKernelGGL(transpose_cvt, dim3(16, 64), dim3(256), 0, stream, kw, kt, 4096, 1024);
  hipLaunchKernelGGL(transpose_cvt, dim3(16, 64), dim3(256), 0, stream, vw, vtw, 4096, 1024);
  hipLaunchKernelGGL(gemm_bt, dim3(48, 32), dim3(256), 0, stream,
                     hb, qt, kt, vtw, Qb, Kb, Vtb, (float*)nullptr, 0);
  hipLaunchKernelGGL(transpose_cvt, dim3(64, 64), dim3(256), 0, stream, ow, ot, 4096, 4096); // hb dead
  hipLaunchKernelGGL(rope_apply_k, dim3(5120), dim3(256), 0, stream, Qb, Kb, pos);
  hipLaunchKernelGGL(flash_swa, dim3(16, 32, 2), dim3(256), 0, stream, Qb, Kb, Vtb, amask, attn);
  hipLaunchKernelGGL(gemm_bt, dim3(32, 32), dim3(256), 0, stream,
                     attn, ot, ot, ot, nullptr, nullptr, nullptr, outp, 1);
}